// Round 5
// baseline (122.989 us; speedup 1.0000x reference)
//
#include <hip/hip_runtime.h>
#include <hip/hip_bf16.h>

#define B_ROWS 4096
#define TWOB   8192
#define DIM    256
#define INV_T  14.285714285714286f  // 1/0.07

#define NT_TILES 32       // 8192/256 col tiles (also row tiles)

typedef __bf16 bf16x8 __attribute__((ext_vector_type(8)));
typedef float  f32x4  __attribute__((ext_vector_type(4)));

// ---------------- kernel 1: row L2-normalize, fp32 -> bf16 ----------------
__global__ __launch_bounds__(256) void normalize_k(const float* __restrict__ zi,
                                                   const float* __restrict__ zj,
                                                   unsigned short* __restrict__ zn,
                                                   float* __restrict__ loss_acc,
                                                   unsigned int* __restrict__ counter) {
    if (blockIdx.x == 0 && threadIdx.x == 0) {
        loss_acc[0] = 0.0f;
        counter[0]  = 0u;
    }
    int wave = threadIdx.x >> 6;
    int lane = threadIdx.x & 63;
    int row  = blockIdx.x * 4 + wave;
    const float* src = (row < B_ROWS) ? (zi + (size_t)row * DIM)
                                      : (zj + (size_t)(row - B_ROWS) * DIM);
    float4 v = reinterpret_cast<const float4*>(src)[lane];
    float ss = v.x * v.x + v.y * v.y + v.z * v.z + v.w * v.w;
#pragma unroll
    for (int off = 32; off >= 1; off >>= 1) ss += __shfl_xor(ss, off);
    float norm = sqrtf(ss);
    norm = fmaxf(norm, 1e-8f);                    // COS_EPS
    float inv = 1.0f / norm;
    ushort4 o;
    o.x = __builtin_bit_cast(unsigned short, __float2bfloat16(v.x * inv));
    o.y = __builtin_bit_cast(unsigned short, __float2bfloat16(v.y * inv));
    o.z = __builtin_bit_cast(unsigned short, __float2bfloat16(v.z * inv));
    o.w = __builtin_bit_cast(unsigned short, __float2bfloat16(v.w * inv));
    reinterpret_cast<ushort4*>(zn)[(size_t)row * 64 + lane] = o;
}

// ---------------- kernel 2: flash NT-Xent main (m201-geometry 8-phase) ----------------
// 256x256 block tile, 8 waves (2M x 4N -> wave tile 128x64), 512 thr, grid 32x32.
// R4 post-mortem: 64x64 wave tile needs 2x the LDS fragment bytes per FLOP -> LDS
// drain (770+ cyc) > MFMA (620) per kstep, serialized by lockstep barrier = 656 TF
// (the documented 2-phase ceiling). 128x64 wave tile flips the ratio (per K32-step:
// LDS 1129 cyc < MFMA 1241 cyc). Schedule = m201 template: per phase {4-8 ds_reads,
// 2 stage loads, barrier, lgkmcnt(0)+sched_barrier, setprio(1), 16 MFMA, setprio(0),
// barrier}; ring-2 dbuf (128 KB LDS); vmcnt(0) once per BK64-step, after the last
// MFMA cluster (youngest stage load >= 1 phase old -> covered). K=256 = 4 BK-steps,
// full-K accumulate (128 acc VGPR), single fused exp epilogue.
__global__ __launch_bounds__(512, 2) void ntxent_main(const unsigned short* __restrict__ znu,
                                                      float* __restrict__ pos,
                                                      float* __restrict__ strip_sums) {
    const __bf16* zn = (const __bf16*)znu;
    // A slot s: lds + s*32768, chunks (rh*2+kt)*8192   (chunk = 128 rows x 32 k)
    // B slot s: lds + 65536 + s*32768, chunks (ch*2+kt)*8192 (chunk = 128 cols x 32 k)
    __shared__ __attribute__((aligned(16))) char lds[131072];

    const int tid  = threadIdx.x;
    const int wave = tid >> 6;               // 0..7
    const int lane = tid & 63;
    const int wr = wave >> 2, wc = wave & 3; // 2 x 4 wave grid, wave tile 128x64
    const int quad = lane >> 4, lc = lane & 15;
    const int mt = blockIdx.x;               // row tile 0..31 (256 rows)
    const int nt = blockIdx.y;               // col tile 0..31 (256 cols)
    const int mrow0 = mt * 256, ncol0 = nt * 256;
    const int posT  = (mt + 16) & 31;        // col tile holding (row+4096)&8191

    // stage offset (proven involution): m = tid>>2 (row-in-chunk, 0..127),
    // kc_g = (tid&3) ^ sw(m), sw(m) = (m&3)^((m>>2)&3)
    int stg;
    { int m = tid >> 2; int kc = (tid & 3) ^ ((m & 3) ^ ((m >> 2) & 3)); stg = m * DIM + kc * 8; }

    // fragment read offsets (same proven swizzle; sw depends only on lc)
    const int sw   = (lc & 3) ^ ((lc >> 2) & 3);
    const int aOff = lc * 64 + ((quad ^ sw) * 16);                    // + mi*1024, chunk (wr*2+kt)
    const int bOff = ((wc & 1) * 64 + lc) * 64 + ((quad ^ sw) * 16);  // + ni*1024, chunk ((wc>>1)*2+kt)

#define STAGE_A(T, RH, KT) do { \
        const __bf16* g_ = zn + (size_t)(mrow0 + (RH) * 128) * DIM + (T) * 64 + (KT) * 32 + stg; \
        __builtin_amdgcn_global_load_lds( \
            (const __attribute__((address_space(1))) void*)g_, \
            (__attribute__((address_space(3))) void*)(lds + ((T) & 1) * 32768 + ((RH) * 2 + (KT)) * 8192 + tid * 16), \
            16, 0, 0); \
    } while (0)

#define STAGE_B(T, CH, KT) do { \
        const __bf16* g_ = zn + (size_t)(ncol0 + (CH) * 128) * DIM + (T) * 64 + (KT) * 32 + stg; \
        __builtin_amdgcn_global_load_lds( \
            (const __attribute__((address_space(1))) void*)g_, \
            (__attribute__((address_space(3))) void*)(lds + 65536 + ((T) & 1) * 32768 + ((CH) * 2 + (KT)) * 8192 + tid * 16), \
            16, 0, 0); \
    } while (0)

// one phase: reads (af for mi-half MH, optionally bfr for kt) + 2 stage loads ->
// barrier -> lgkmcnt(0)+sched_barrier (rule 18) -> setprio(1) -> 16 MFMA -> setprio(0)
// -> [last phase of step: vmcnt(0), overlapped with MFMA pipe drain] -> barrier.
#define PH(T, KT, MH, READB, STAGEOP, DOVM) do { \
        _Pragma("unroll") \
        for (int q = 0; q < 4; ++q) \
            af_[q] = *(const bf16x8*)(lds + ((T) & 1) * 32768 + (wr * 2 + (KT)) * 8192 + ((MH) * 4 + q) * 1024 + aOff); \
        if (READB) { \
            _Pragma("unroll") \
            for (int q = 0; q < 4; ++q) \
                bfr_[q] = *(const bf16x8*)(lds + 65536 + ((T) & 1) * 32768 + ((wc >> 1) * 2 + (KT)) * 8192 + q * 1024 + bOff); \
        } \
        STAGEOP; \
        __builtin_amdgcn_s_barrier(); \
        asm volatile("s_waitcnt lgkmcnt(0)" ::: "memory"); \
        __builtin_amdgcn_sched_barrier(0); \
        __builtin_amdgcn_s_setprio(1); \
        _Pragma("unroll") \
        for (int q = 0; q < 4; ++q) \
            _Pragma("unroll") \
            for (int n = 0; n < 4; ++n) \
                acc[(MH) * 4 + q][n] = __builtin_amdgcn_mfma_f32_16x16x32_bf16( \
                    af_[q], bfr_[n], acc[(MH) * 4 + q][n], 0, 0, 0); \
        __builtin_amdgcn_s_setprio(0); \
        if (DOVM) asm volatile("s_waitcnt vmcnt(0)" ::: "memory"); \
        __builtin_amdgcn_s_barrier(); \
    } while (0)

// one BK64-step: 4 phases (kt x mi-half); stage of step T+1 spread 2 loads/phase
#define STEP(T, DOSTAGE) do { \
        PH(T, 0, 0, 1, if (DOSTAGE) { STAGE_A((T) + 1, 0, 0); STAGE_A((T) + 1, 0, 1); }, 0); \
        PH(T, 0, 1, 0, if (DOSTAGE) { STAGE_A((T) + 1, 1, 0); STAGE_A((T) + 1, 1, 1); }, 0); \
        PH(T, 1, 0, 1, if (DOSTAGE) { STAGE_B((T) + 1, 0, 0); STAGE_B((T) + 1, 0, 1); }, 0); \
        PH(T, 1, 1, 0, if (DOSTAGE) { STAGE_B((T) + 1, 1, 0); STAGE_B((T) + 1, 1, 1); }, 1); \
    } while (0)

    // ---- prologue: stage BK0 (both A and B), drain once, barrier ----
    STAGE_A(0, 0, 0); STAGE_A(0, 0, 1); STAGE_A(0, 1, 0); STAGE_A(0, 1, 1);
    STAGE_B(0, 0, 0); STAGE_B(0, 0, 1); STAGE_B(0, 1, 0); STAGE_B(0, 1, 1);

    f32x4 acc[8][4];
#pragma unroll
    for (int mi = 0; mi < 8; ++mi)
#pragma unroll
        for (int ni = 0; ni < 4; ++ni) acc[mi][ni] = f32x4{0.f, 0.f, 0.f, 0.f};

    bf16x8 af_[4], bfr_[4];

    asm volatile("s_waitcnt vmcnt(0)" ::: "memory");
    __builtin_amdgcn_s_barrier();

    STEP(0, 1);
    STEP(1, 1);
    STEP(2, 1);
    STEP(3, 0);

    // ---- epilogue: exp + row sums; diag mask / pos capture in special tiles ----
    const bool special = (nt == mt) || (nt == posT);
    float rsum[8][4];
    float posv[8];
    int   posm[8];
#pragma unroll
    for (int mi = 0; mi < 8; ++mi) {
        posv[mi] = 0.f; posm[mi] = -1;
#pragma unroll
        for (int r = 0; r < 4; ++r) rsum[mi][r] = 0.0f;
    }
#pragma unroll
    for (int mi = 0; mi < 8; ++mi) {
#pragma unroll
        for (int ni = 0; ni < 4; ++ni) {
            f32x4 a_ = acc[mi][ni];
#pragma unroll
            for (int r = 0; r < 4; ++r) {
                float logit = a_[r] * INV_T;
                float e = __expf(logit);
                if (special) {
                    int gr = mrow0 + wr * 128 + mi * 16 + quad * 4 + r;
                    int gc = ncol0 + wc * 64 + ni * 16 + lc;
                    if (gc == ((gr + B_ROWS) & (TWOB - 1))) { posv[mi] = logit; posm[mi] = gr; }
                    if (gr == gc) e = 0.0f;    // diagonal mask
                }
                rsum[mi][r] += e;
            }
        }
    }
#pragma unroll
    for (int mi = 0; mi < 8; ++mi)
        if (posm[mi] >= 0) pos[posm[mi]] = posv[mi];

    // all LDS reads done (lgkmcnt(0) per phase); alias rowsumL onto lds
    __syncthreads();
    float* rowsumL = (float*)lds;   // [4 wc][256 rows]
#pragma unroll
    for (int mi = 0; mi < 8; ++mi) {
#pragma unroll
        for (int r = 0; r < 4; ++r) {
            float v = rsum[mi][r];
            v += __shfl_xor(v, 1);
            v += __shfl_xor(v, 2);
            v += __shfl_xor(v, 4);
            v += __shfl_xor(v, 8);
            if (lc == 0) rowsumL[wc * 256 + wr * 128 + mi * 16 + quad * 4 + r] = v;
        }
    }
    __syncthreads();
    if (tid < 256)
        strip_sums[(size_t)nt * TWOB + mrow0 + tid] =
            rowsumL[tid] + rowsumL[256 + tid] + rowsumL[512 + tid] + rowsumL[768 + tid];
}

// ---------------- kernel 3: loss = mean(log(sumexp) - pos) ----------------
__global__ __launch_bounds__(256) void finalize_k(const float* __restrict__ strip_sums,
                                                  const float* __restrict__ pos,
                                                  float* __restrict__ loss_acc,
                                                  unsigned int* __restrict__ counter,
                                                  float* __restrict__ out) {
    __shared__ float wsums[4];
    const int tid = threadIdx.x;
    const int r   = blockIdx.x * 256 + tid;
    float s = 0.0f;
#pragma unroll
    for (int st = 0; st < NT_TILES; ++st) s += strip_sums[(size_t)st * TWOB + r];
    float local = logf(s) - pos[r];
#pragma unroll
    for (int off = 32; off >= 1; off >>= 1) local += __shfl_xor(local, off);
    if ((tid & 63) == 0) wsums[tid >> 6] = local;
    __syncthreads();
    if (tid == 0) {
        float bsum = wsums[0] + wsums[1] + wsums[2] + wsums[3];
        atomicAdd(loss_acc, bsum);
        __threadfence();                              // order loss add before counter add
        unsigned int done = atomicAdd(counter, 1u);
        if (done == gridDim.x - 1) {
            float total = atomicAdd(loss_acc, 0.0f);  // device-scope atomic read
            out[0] = total / (float)TWOB;
        }
    }
}

extern "C" void kernel_launch(void* const* d_in, const int* in_sizes, int n_in,
                              void* d_out, int out_size, void* d_ws, size_t ws_size,
                              hipStream_t stream) {
    const float* zi = (const float*)d_in[0];
    const float* zj = (const float*)d_in[1];
    // ws layout: zn (4 MB) | pos (32 KB) | strip_sums (1 MB) | loss_acc | counter
    unsigned short* zn = (unsigned short*)d_ws;
    float* pos        = (float*)((char*)d_ws + (size_t)TWOB * DIM * 2);
    float* strip_sums = pos + TWOB;
    float* loss_acc   = strip_sums + (size_t)NT_TILES * TWOB;
    unsigned int* counter = (unsigned int*)(loss_acc + 1);
    float* out = (float*)d_out;

    normalize_k<<<dim3(TWOB / 4), 256, 0, stream>>>(zi, zj, zn, loss_acc, counter);
    ntxent_main<<<dim3(NT_TILES, NT_TILES), 512, 0, stream>>>(zn, pos, strip_sums);
    finalize_k<<<dim3(TWOB / 256), 256, 0, stream>>>(strip_sums, pos, loss_acc, counter, out);
}

// Round 6
// 98.864 us; speedup vs baseline: 1.2440x; 1.2440x over previous
//
#include <hip/hip_runtime.h>
#include <hip/hip_bf16.h>

#define B_ROWS 4096
#define TWOB   8192
#define DIM    256
#define INV_T  14.285714285714286f  // 1/0.07

#define BM 128
#define BN 128
#define NQ 8              // col-chunk blocks per row tile (4 tiles each, chunk 7 may have 5)
#define NSLOT 41          // strip_sums slots: j=1..32 col-sum slots, 33..40 row-sum slots

typedef __bf16 bf16x8 __attribute__((ext_vector_type(8)));
typedef float  f32x4  __attribute__((ext_vector_type(4)));

// ---------------- kernel 1: row L2-normalize, fp32 -> bf16 ----------------
// Also zeroes the finalize accumulators (ws is re-poisoned 0xAA before every launch).
__global__ __launch_bounds__(256) void normalize_k(const float* __restrict__ zi,
                                                   const float* __restrict__ zj,
                                                   unsigned short* __restrict__ zn,
                                                   float* __restrict__ loss_acc,
                                                   unsigned int* __restrict__ counter) {
    if (blockIdx.x == 0 && threadIdx.x == 0) {
        loss_acc[0] = 0.0f;
        counter[0]  = 0u;
    }
    int wave = threadIdx.x >> 6;
    int lane = threadIdx.x & 63;
    int row  = blockIdx.x * 4 + wave;             // 2048 blocks * 4 waves = 8192 rows
    const float* src = (row < B_ROWS) ? (zi + (size_t)row * DIM)
                                      : (zj + (size_t)(row - B_ROWS) * DIM);
    float4 v = reinterpret_cast<const float4*>(src)[lane];   // 64 lanes * 4 = 256
    float ss = v.x * v.x + v.y * v.y + v.z * v.z + v.w * v.w;
#pragma unroll
    for (int off = 32; off >= 1; off >>= 1) ss += __shfl_xor(ss, off);
    float norm = sqrtf(ss);
    norm = fmaxf(norm, 1e-8f);                    // COS_EPS
    float inv = 1.0f / norm;
    ushort4 o;
    o.x = __builtin_bit_cast(unsigned short, __float2bfloat16(v.x * inv));
    o.y = __builtin_bit_cast(unsigned short, __float2bfloat16(v.y * inv));
    o.z = __builtin_bit_cast(unsigned short, __float2bfloat16(v.z * inv));
    o.w = __builtin_bit_cast(unsigned short, __float2bfloat16(v.w * inv));
    reinterpret_cast<ushort4*>(zn)[(size_t)row * 64 + lane] = o;
}

// ---------------- kernel 2: symmetric flash NT-Xent main ----------------
// sim = zn@zn^T is SYMMETRIC: each off-diagonal tile (r,c) supplies row sums for
// rows of r (rsum regs, flushed at end to slot 33+q) AND, via its col sums, row
// sums for rows of c (flushed per tile to slot j=(c-r)&63). Upper band only:
// block (rt,q) handles col tiles c=(rt+j)&63, j in {4q..4q+3} (+ j=32 for q==7,
// rt<32). 2080 of 4096 tiles -> half the MFMA work. Compute loop = R0's verified
// 49.9us structure verbatim (A LDS-resident staged once, B ping-pong staged one
// kstep ahead, 80 KB LDS, 2 blocks/CU). pos pairs live only in j==32 tiles; each
// element writes pos[gr] and pos[gr+4096]. colsum buffer aliases Bs[1] (only
// Bs[0] has an in-flight stage during the epilogue).
__global__ __launch_bounds__(256) void ntxent_main(const unsigned short* __restrict__ znu,
                                                   float* __restrict__ pos,
                                                   float* __restrict__ strip_sums) {
    const __bf16* zn = (const __bf16*)znu;
    __shared__ __attribute__((aligned(16))) __bf16 As[8][BM * 32];   // 8 kt-chunks x 8 KB = 64 KB
    __shared__ __attribute__((aligned(16))) __bf16 Bs[2][BN * 32];   // ping-pong, 16 KB

    const int tid  = threadIdx.x;
    const int wave = tid >> 6;
    const int lane = tid & 63;
    const int wr = wave >> 1, wc = wave & 1;
    const int quad = lane >> 4, lc = lane & 15;
    const int rt = blockIdx.x;           // row-tile 0..63
    const int q  = blockIdx.y;           // col-chunk 0..7
    const int q4 = q * 4;
    const int row0 = rt * BM;
    const int NCT = (q == 7 && rt < 32) ? 5 : 4;
#define COLOF(i) ((rt + (((i) == 4) ? 32 : (q4 + (i)))) & 63)

    // staging: per-lane global element offsets for this wave's two 1KB chunks per stage.
    // chunk c = j*64+lane -> (m=c>>2, kc_lds=c&3); source kc_g = kc_lds ^ sw(m)  (involution)
    int stg_off[2];
#pragma unroll
    for (int t = 0; t < 2; ++t) {
        int c  = (wave * 2 + t) * 64 + lane;
        int m  = c >> 2;
        int kc = (c & 3) ^ ((m & 3) ^ ((m >> 2) & 3));
        stg_off[t] = m * DIM + kc * 8;
    }

    // fragment-read byte offsets within one 8KB chunk (swizzle depends only on m&15 == lc)
    const int sw    = (lc & 3) ^ ((lc >> 2) & 3);
    const int aBase = (wr * 64 + lc) * 64 + ((quad ^ sw) * 16);
    const int bBase = (wc * 64 + lc) * 64 + ((quad ^ sw) * 16);

    // ---- prologue: stage full A (8 chunks) + first B chunk ----
#pragma unroll
    for (int kt = 0; kt < 8; ++kt) {
#pragma unroll
        for (int t = 0; t < 2; ++t) {
            const int j = wave * 2 + t;
            const __bf16* ga = zn + row0 * DIM + kt * 32 + stg_off[t];
            __builtin_amdgcn_global_load_lds(
                (const __attribute__((address_space(1))) void*)ga,
                (__attribute__((address_space(3))) void*)((char*)As + kt * 8192 + j * 1024), 16, 0, 0);
        }
    }
    {
        const int col0 = COLOF(0) * BN;
#pragma unroll
        for (int t = 0; t < 2; ++t) {
            const int j = wave * 2 + t;
            const __bf16* gb = zn + col0 * DIM + stg_off[t];
            __builtin_amdgcn_global_load_lds(
                (const __attribute__((address_space(1))) void*)gb,
                (__attribute__((address_space(3))) void*)((char*)Bs + j * 1024), 16, 0, 0);
        }
    }

    f32x4 acc[4][4];
    float rsum[4][4];
    float posv[4] = {0.f, 0.f, 0.f, 0.f};
    int   posm[4] = {-1, -1, -1, -1};
#pragma unroll
    for (int mi = 0; mi < 4; ++mi)
#pragma unroll
        for (int r = 0; r < 4; ++r) rsum[mi][r] = 0.0f;

    for (int ct = 0; ct < NCT; ++ct) {
        const int jdist = (ct == 4) ? 32 : (q4 + ct);
        const int c     = (rt + jdist) & 63;
        const int col0  = c * BN;
#pragma unroll
        for (int mi = 0; mi < 4; ++mi)
#pragma unroll
            for (int ni = 0; ni < 4; ++ni) acc[mi][ni] = f32x4{0.f, 0.f, 0.f, 0.f};

#pragma unroll
        for (int kt = 0; kt < 8; ++kt) {
            // barrier: (a) drains the B stage issued one iteration ago (covered
            // by that iteration's compute), (b) guards reuse of Bs[kt+1 & 1].
            __syncthreads();

            // stage next B chunk into the other buffer
            {
                const int nct = (kt == 7) ? ct + 1 : ct;
                const int nkt = (kt + 1) & 7;
                if (nct < NCT) {
                    const int ncol0 = COLOF(nct) * BN;
#pragma unroll
                    for (int t = 0; t < 2; ++t) {
                        const int j = wave * 2 + t;
                        const __bf16* gb = zn + ncol0 * DIM + nkt * 32 + stg_off[t];
                        __builtin_amdgcn_global_load_lds(
                            (const __attribute__((address_space(1))) void*)gb,
                            (__attribute__((address_space(3))) void*)((char*)Bs + ((kt + 1) & 1) * 8192 + j * 1024),
                            16, 0, 0);
                    }
                }
            }

            bf16x8 af[4], bfr[4];
#pragma unroll
            for (int mi = 0; mi < 4; ++mi)
                af[mi] = *(const bf16x8*)((const char*)As + kt * 8192 + aBase + mi * 1024);
#pragma unroll
            for (int ni = 0; ni < 4; ++ni)
                bfr[ni] = *(const bf16x8*)((const char*)Bs + (kt & 1) * 8192 + bBase + ni * 1024);
#pragma unroll
            for (int mi = 0; mi < 4; ++mi)
#pragma unroll
                for (int ni = 0; ni < 4; ++ni)
                    acc[mi][ni] = __builtin_amdgcn_mfma_f32_16x16x32_bf16(
                        af[mi], bfr[ni], acc[mi][ni], 0, 0, 0);
        }

        // epilogue: exp + row sums (C/D layout: row = quad*4+reg, col = lc) + col sums.
        const bool isDiag = (jdist == 0);
        const bool isPos  = (jdist == 32);
        float cadd[4] = {0.f, 0.f, 0.f, 0.f};
#pragma unroll
        for (int mi = 0; mi < 4; ++mi) {
#pragma unroll
            for (int ni = 0; ni < 4; ++ni) {
                f32x4 a = acc[mi][ni];
#pragma unroll
                for (int r = 0; r < 4; ++r) {
                    float logit = a[r] * INV_T;
                    float e = __expf(logit);
                    if (isDiag || isPos) {
                        int gr = row0 + wr * 64 + mi * 16 + quad * 4 + r;
                        int gc = col0 + wc * 64 + ni * 16 + lc;
                        if (isPos && gc == gr + B_ROWS) { posv[mi] = logit; posm[mi] = gr; }
                        if (isDiag && gr == gc) e = 0.0f;    // diagonal mask
                    }
                    rsum[mi][r] += e;
                    cadd[ni]    += e;
                }
            }
        }

        // col-sum flush (transpose contribution -> rows of tile c), skip diagonal tile
        if (!isDiag) {
#pragma unroll
            for (int ni = 0; ni < 4; ++ni) {
                cadd[ni] += __shfl_xor(cadd[ni], 16);   // sum over quad bit 0
                cadd[ni] += __shfl_xor(cadd[ni], 32);   // sum over quad bit 1
            }
            __syncthreads();   // all waves done reading Bs[1]; only Bs[0] stage in flight
            float* colsumL = (float*)((char*)Bs + 8192);   // alias Bs[1], [2][128]
            if (quad == 0) {
#pragma unroll
                for (int ni = 0; ni < 4; ++ni)
                    colsumL[wr * 128 + wc * 64 + ni * 16 + lc] = cadd[ni];
            }
            __syncthreads();
            if (tid < BM)
                strip_sums[(size_t)jdist * TWOB + col0 + tid] = colsumL[tid] + colsumL[BM + tid];
        }
    }

    // deferred pos stores: j==32 tiles hold both directions of each positive pair
#pragma unroll
    for (int mi = 0; mi < 4; ++mi)
        if (posm[mi] >= 0) {
            pos[posm[mi]] = posv[mi];
            pos[posm[mi] + B_ROWS] = posv[mi];
        }

    // row-sum flush; alias rowsumL onto As (all MFMA/ds_reads of As are done)
    __syncthreads();
    float* rowsumL = (float*)As;         // [2][BM]
#pragma unroll
    for (int mi = 0; mi < 4; ++mi) {
#pragma unroll
        for (int r = 0; r < 4; ++r) {
            float v = rsum[mi][r];
            v += __shfl_xor(v, 1);
            v += __shfl_xor(v, 2);
            v += __shfl_xor(v, 4);
            v += __shfl_xor(v, 8);
            if (lc == 0) rowsumL[wc * BM + wr * 64 + mi * 16 + quad * 4 + r] = v;
        }
    }
    __syncthreads();
    if (tid < BM)
        strip_sums[(size_t)(33 + q) * TWOB + row0 + tid] = rowsumL[tid] + rowsumL[BM + tid];
}

// ---------------- kernel 3: loss = mean(log(sumexp) - pos) ----------------
// Row r sums: col-sum slots j=1..31 (all rows), j=32 only for rows >= 4096
// (tiles c<32 get their distance-32 partner via the row-sum path), row-sum
// slots 33..40. Coverage per row = 64 tiles exactly.
__global__ __launch_bounds__(256) void finalize_k(const float* __restrict__ strip_sums,
                                                  const float* __restrict__ pos,
                                                  float* __restrict__ loss_acc,
                                                  unsigned int* __restrict__ counter,
                                                  float* __restrict__ out) {
    __shared__ float wsums[4];
    const int tid = threadIdx.x;
    const int r   = blockIdx.x * 256 + tid;
    float s = 0.0f;
#pragma unroll
    for (int j = 1; j <= 31; ++j) s += strip_sums[(size_t)j * TWOB + r];
    if (r >= B_ROWS) s += strip_sums[(size_t)32 * TWOB + r];
#pragma unroll
    for (int qq = 0; qq < NQ; ++qq) s += strip_sums[(size_t)(33 + qq) * TWOB + r];
    float local = logf(s) - pos[r];
#pragma unroll
    for (int off = 32; off >= 1; off >>= 1) local += __shfl_xor(local, off);
    if ((tid & 63) == 0) wsums[tid >> 6] = local;
    __syncthreads();
    if (tid == 0) {
        float bsum = wsums[0] + wsums[1] + wsums[2] + wsums[3];
        atomicAdd(loss_acc, bsum);
        __threadfence();                              // order loss add before counter add
        unsigned int done = atomicAdd(counter, 1u);
        if (done == gridDim.x - 1) {
            float total = atomicAdd(loss_acc, 0.0f);  // device-scope atomic read
            out[0] = total / (float)TWOB;
        }
    }
}

extern "C" void kernel_launch(void* const* d_in, const int* in_sizes, int n_in,
                              void* d_out, int out_size, void* d_ws, size_t ws_size,
                              hipStream_t stream) {
    const float* zi = (const float*)d_in[0];
    const float* zj = (const float*)d_in[1];
    // ws layout: zn (4 MB) | pos (32 KB) | strip_sums (41 slots x 32 KB = 1.31 MB) | loss_acc | counter
    unsigned short* zn = (unsigned short*)d_ws;
    float* pos        = (float*)((char*)d_ws + (size_t)TWOB * DIM * 2);
    float* strip_sums = pos + TWOB;
    float* loss_acc   = strip_sums + (size_t)NSLOT * TWOB;
    unsigned int* counter = (unsigned int*)(loss_acc + 1);
    float* out = (float*)d_out;

    normalize_k<<<dim3(TWOB / 4), 256, 0, stream>>>(zi, zj, zn, loss_acc, counter);
    ntxent_main<<<dim3(64, NQ), 256, 0, stream>>>(zn, pos, strip_sums);
    finalize_k<<<dim3(TWOB / 256), 256, 0, stream>>>(strip_sums, pos, loss_acc, counter, out);
}